// Round 12
// baseline (1061.234 us; speedup 1.0000x reference)
//
#include <hip/hip_runtime.h>
#include <hip/hip_cooperative_groups.h>
#include <stdint.h>

namespace cg = cooperative_groups;

#define NTOK   4096
#define DMODEL 1024
#define HFF    4096
#define NEXP   8
#define BM     256
#define BK     64
#define MAX_MT 39
#define KT1    16                    // DMODEL/BK
#define KT2    64                    // HFF/BK
#define PARTE  ((size_t)MAX_MT * 256 * DMODEL)   // u16 elems per partial
#define N_PREW1 2048                 // 8*16*16
#define N_ARR   (MAX_MT * 16)        // 624
#define N_G1    (MAX_MT * 16)        // 624
#define N_PREW2 2048                 // 8*4*64
#define N_G2    (MAX_MT * 16)        // 624 (4 nt x 4 kh)

typedef unsigned int   u32;
typedef unsigned short u16;
typedef u32   u32x4  __attribute__((ext_vector_type(4)));
typedef short s16x8  __attribute__((ext_vector_type(8)));
typedef float f32x4  __attribute__((ext_vector_type(4)));

__device__ __forceinline__ u16 f2bf(float f) {
  u32 u = __builtin_bit_cast(u32, f);
  return (u16)((u + 0x7FFFu + ((u >> 16) & 1u)) >> 16);   // RNE
}
__device__ __forceinline__ float bf2f(u32 lo16) {
  return __builtin_bit_cast(float, lo16 << 16);
}
__device__ __forceinline__ void gld_lds16(const void* g, void* l) {
  __builtin_amdgcn_global_load_lds((const __attribute__((address_space(1))) void*)g,
                                   (__attribute__((address_space(3))) void*)l, 16, 0, 0);
}

struct MoEP {
  const float *x, *Wg, *bg, *W1, *b1, *W2, *b2, *gamma, *beta;
  float* out;
  u32x4 *Ap1, *Bp1, *Bp2, *hImg;
  u16* part;                        // 4 bf16 partials (aliases Ap1/Bp1)
  int *ctr, *counts, *cursor, *poffset, *tok_of_slot, *mtile_e, *token_slot, *top_idx;
  float* top_w;
};

// ---- fragment-image format (per 64k x 256n tile, 2048 u32x4 = 32KB) ----------
// entry g*64+l: g=(k>>5)*16+(n>>4), l=((k>>3)&3)*16+(n&15), elem j=k&7 -> T[k][n]

// ------- W [K][N] fp32 -> fragment image tile (512 threads) -------------------
__device__ void prearr512(const float* __restrict__ W, u32x4* __restrict__ Bp,
                          int K, int N, int NT, int KT, int tile, u32x4* LB) {
  int kt  = tile % KT; int rem = tile / KT;
  int nt  = rem % NT;  int e   = rem / NT;
  u32* img = (u32*)LB;
  const int tid = threadIdx.x;
  const float* src = W + ((size_t)e * K + (size_t)kt * BK) * N + (size_t)nt * 256;
  const int c4 = (tid & 63) * 4;
  const int k0 = (tid >> 6) * 2;     // 0,2,..,14
#pragma unroll
  for (int p = 0; p < 4; ++p) {
    const int k = k0 + p * 16;       // even
    float4 v0 = *(const float4*)(src + (size_t)k * N + c4);
    float4 v1 = *(const float4*)(src + (size_t)(k + 1) * N + c4);
    u32 w[4] = { (u32)f2bf(v0.x) | ((u32)f2bf(v1.x) << 16),
                 (u32)f2bf(v0.y) | ((u32)f2bf(v1.y) << 16),
                 (u32)f2bf(v0.z) | ((u32)f2bf(v1.z) << 16),
                 (u32)f2bf(v0.w) | ((u32)f2bf(v1.w) << 16) };
#pragma unroll
    for (int q = 0; q < 4; ++q) {
      const int n = c4 + q;
      const int ent = ((k >> 5) * 16 + (n >> 4)) * 64 + ((k >> 3) & 3) * 16 + (n & 15);
      img[ent * 4 + ((k & 7) >> 1)] = w[q];
    }
  }
  __syncthreads();
  u32x4* outp = Bp + (size_t)tile * 2048;
#pragma unroll
  for (int c = 0; c < 4; ++c) outp[c * 512 + tid] = LB[c * 512 + tid];
}

// ---- gather tokens -> A fragment image tile (512 threads) --------------------
__device__ void arrangeA512(const MoEP& p, int j, u32x4* LB) {
  const int mt = j >> 4, kt = j & 15;
  if (p.mtile_e[mt] < 0) return;
  u16* imgu = (u16*)LB;
  const int tid = threadIdx.x;
  const int lane16 = tid & 15, rp = tid >> 4;   // rp 0..31
#pragma unroll
  for (int q = 0; q < 8; ++q) {
    const int row = rp + q * 32;
    const int tok = p.tok_of_slot[mt * BM + row];
    float4 v = *(const float4*)(p.x + (size_t)tok * DMODEL + kt * BK + lane16 * 4);
    const int g = (lane16 >> 3) * 16 + (row >> 4);
    const int l = ((lane16 >> 1) & 3) * 16 + (row & 15);
    u32* dst = (u32*)(imgu + (size_t)(g * 64 + l) * 8 + (lane16 & 1) * 4);
    dst[0] = (u32)f2bf(v.x) | ((u32)f2bf(v.y) << 16);
    dst[1] = (u32)f2bf(v.z) | ((u32)f2bf(v.w) << 16);
  }
  __syncthreads();
  u32x4* outp = p.Ap1 + (size_t)j * 2048;
#pragma unroll
  for (int c = 0; c < 4; ++c) outp[c * 512 + tid] = LB[c * 512 + tid];
}

// ---- gating for one token (512 threads) ---------------------------------------
__device__ void gating512(const MoEP& p, int t, u32x4* LB) {
  const int tid = threadIdx.x;
  float acc[NEXP];
#pragma unroll
  for (int e = 0; e < NEXP; ++e) acc[e] = 0.f;
  const float* xr = p.x + (size_t)t * DMODEL;
#pragma unroll
  for (int h = 0; h < 2; ++h) {
    const int d = tid + h * 512;
    float xv = xr[d];
    const float4* wg = (const float4*)(p.Wg + d * NEXP);
    float4 a = wg[0], b = wg[1];
    acc[0] += xv * a.x; acc[1] += xv * a.y; acc[2] += xv * a.z; acc[3] += xv * a.w;
    acc[4] += xv * b.x; acc[5] += xv * b.y; acc[6] += xv * b.z; acc[7] += xv * b.w;
  }
#pragma unroll
  for (int e = 0; e < NEXP; ++e)
#pragma unroll
    for (int off = 32; off; off >>= 1) acc[e] += __shfl_down(acc[e], off);
  float* red = (float*)LB;           // [8 waves][8 experts]
  const int wv = tid >> 6;
  if ((tid & 63) == 0)
#pragma unroll
    for (int e = 0; e < NEXP; ++e) red[wv * NEXP + e] = acc[e];
  __syncthreads();
  if (tid == 0) {
    float v0 = -1e30f, v1 = -1e30f; int i0 = 0, i1 = 0;
    for (int e = 0; e < NEXP; ++e) {
      float l = p.bg[e];
      for (int w = 0; w < 8; ++w) l += red[w * NEXP + e];
      if (l > v0)      { v1 = v0; i1 = i0; v0 = l; i0 = e; }
      else if (l > v1) { v1 = l; i1 = e; }
    }
    float e1 = expf(v1 - v0);
    float w0 = 1.f / (1.f + e1);
    p.top_idx[2 * t] = i0; p.top_idx[2 * t + 1] = i1;
    p.top_w[2 * t] = w0;   p.top_w[2 * t + 1] = e1 * w0;
    atomicAdd(&p.counts[i0], 1); atomicAdd(&p.counts[i1], 1);
  }
  __syncthreads();
}

// ---- GEMM inner loop (R8 ring schedule, measured best) ------------------------
__device__ void gemm_body(const u32x4* abase, const u32x4* bbase, int NH,
                          u32x4* LB, f32x4 (&acc)[8][4]) {
  u32x4* AsR = LB;
  u32x4* BsR = LB + 4096;
  const int tid  = threadIdx.x;
  const int lane = tid & 63;
  const int wv   = tid >> 6;
  const int wm   = wv >> 2;
  const int wn   = wv & 3;

  auto stageA = [&](int H) {
    const u32x4* s = abase + (size_t)H * 1024; const int q = H & 3;
    gld_lds16(s + (wv * 2 + 0) * 64 + lane, &AsR[q * 1024 + (wv * 2 + 0) * 64]);
    gld_lds16(s + (wv * 2 + 1) * 64 + lane, &AsR[q * 1024 + (wv * 2 + 1) * 64]);
  };
  auto stageB = [&](int H) {
    const u32x4* s = bbase + (size_t)H * 1024; const int q = H & 3;
    gld_lds16(s + (wv * 2 + 0) * 64 + lane, &BsR[q * 1024 + (wv * 2 + 0) * 64]);
    gld_lds16(s + (wv * 2 + 1) * 64 + lane, &BsR[q * 1024 + (wv * 2 + 1) * 64]);
  };

  stageA(0); stageB(0); stageA(1); stageB(1); stageA(2); stageB(2);

  for (int H = 0; H < NH; ++H) {
    const int rem = NH - 1 - H;
    if (rem >= 2)      asm volatile("s_waitcnt vmcnt(8)" ::: "memory");
    else if (rem == 1) asm volatile("s_waitcnt vmcnt(4)" ::: "memory");
    else               asm volatile("s_waitcnt vmcnt(0)" ::: "memory");
    __builtin_amdgcn_sched_barrier(0);
    __builtin_amdgcn_s_barrier();
    __builtin_amdgcn_sched_barrier(0);
    const u32x4* Ah = AsR + (H & 3) * 1024;
    const u32x4* Bh = BsR + (H & 3) * 1024;
    const bool st = (H + 3 < NH);
    if (st) stageA(H + 3);
    __builtin_amdgcn_sched_barrier(0);
    s16x8 a[4], b[4];
#pragma unroll
    for (int ni = 0; ni < 4; ++ni)
      b[ni] = __builtin_bit_cast(s16x8, Bh[(wn * 4 + ni) * 64 + lane]);
#pragma unroll
    for (int mi = 0; mi < 4; ++mi)
      a[mi] = __builtin_bit_cast(s16x8, Ah[(wm * 8 + mi) * 64 + lane]);
    __builtin_amdgcn_s_setprio(1);
#pragma unroll
    for (int mi = 0; mi < 4; ++mi)
#pragma unroll
      for (int ni = 0; ni < 4; ++ni)
        acc[mi][ni] = __builtin_amdgcn_mfma_f32_16x16x32_bf16(a[mi], b[ni], acc[mi][ni], 0, 0, 0);
    __builtin_amdgcn_s_setprio(0);
    __builtin_amdgcn_sched_barrier(0);
    if (st) stageB(H + 3);
    __builtin_amdgcn_sched_barrier(0);
#pragma unroll
    for (int mi = 0; mi < 4; ++mi)
      a[mi] = __builtin_bit_cast(s16x8, Ah[(wm * 8 + 4 + mi) * 64 + lane]);
    __builtin_amdgcn_s_setprio(1);
#pragma unroll
    for (int mi = 0; mi < 4; ++mi)
#pragma unroll
      for (int ni = 0; ni < 4; ++ni)
        acc[4 + mi][ni] = __builtin_amdgcn_mfma_f32_16x16x32_bf16(a[mi], b[ni], acc[4 + mi][ni], 0, 0, 0);
    __builtin_amdgcn_s_setprio(0);
  }
  __syncthreads();
}

// ---- GEMM1 item: (mt, nt1), GELU+bias, write h as GEMM2 A-images --------------
__device__ void gemm1_item(const MoEP& p, int i, u32x4* LB) {
  const int mt = i % MAX_MT, nt = i / MAX_MT;
  const int e = p.mtile_e[mt];
  if (e < 0) return;
  f32x4 acc[8][4] = {};
  gemm_body(p.Ap1 + (size_t)mt * 32 * 1024,
            p.Bp1 + (size_t)(e * 16 + nt) * 32 * 1024, 32, LB, acc);
  const int tid = threadIdx.x, lane = tid & 63;
  const int wv = tid >> 6, wm = wv >> 2, wn = wv & 3;
  const int rbase = ((lane >> 4) << 2), c16 = lane & 15;
  u16* cimg = (u16*)LB;
  float bv[4];
#pragma unroll
  for (int ni = 0; ni < 4; ++ni)
    bv[ni] = p.b1[(size_t)e * HFF + nt * 256 + wn * 64 + ni * 16 + c16];
#pragma unroll
  for (int mi = 0; mi < 8; ++mi)
#pragma unroll
    for (int ni = 0; ni < 4; ++ni)
#pragma unroll
      for (int r = 0; r < 4; ++r) {
        const int row = wm * 128 + mi * 16 + rbase + r;
        const int col = wn * 64 + ni * 16 + c16;
        float v = acc[mi][ni][r] + bv[ni];
        v = 0.5f * v * (1.0f + erff(v * 0.70710678118654752f));
        const int k = col & 63;
        const int ent = (col >> 6) * 2048
                      + ((k >> 5) * 16 + (row >> 4)) * 64
                      + ((k >> 3) & 3) * 16 + (row & 15);
        cimg[ent * 8 + (k & 7)] = f2bf(v);
      }
  __syncthreads();
  u32x4* outp = p.hImg + ((size_t)mt * KT2 + nt * 4) * 2048;
#pragma unroll
  for (int c = 0; c < 16; ++c) outp[c * 512 + tid] = LB[c * 512 + tid];
}

// ---- GEMM2 item: (mt, nt2, kh) split-K=4, bf16 partial, bias deferred ---------
__device__ void gemm2_item(const MoEP& p, int i, u32x4* LB) {
  const int mt = i % MAX_MT;
  const int q  = i / MAX_MT;
  const int nt2 = q & 3, kh = q >> 2;
  const int e = p.mtile_e[mt];
  if (e < 0) return;
  f32x4 acc[8][4] = {};
  gemm_body(p.hImg + ((size_t)mt * 128 + kh * 32) * 1024,
            p.Bp2 + ((size_t)(e * 4 + nt2) * 128 + kh * 32) * 1024, 32, LB, acc);
  const int tid = threadIdx.x, lane = tid & 63;
  const int wv = tid >> 6, wm = wv >> 2, wn = wv & 3;
  const int rbase = ((lane >> 4) << 2), c16 = lane & 15;
  u16* o = p.part + (size_t)kh * PARTE + (size_t)mt * 256 * DMODEL + nt2 * 256;
#pragma unroll
  for (int mi = 0; mi < 8; ++mi)
#pragma unroll
    for (int ni = 0; ni < 4; ++ni)
#pragma unroll
      for (int r = 0; r < 4; ++r) {
        const int row = wm * 128 + mi * 16 + rbase + r;
        o[(size_t)row * DMODEL + wn * 64 + ni * 16 + c16] = f2bf(acc[mi][ni][r]);
      }
}

// ---- combine one token (512 threads): 4 partials + bias, residual, LN ---------
__device__ void combine512(const MoEP& p, int t, u32x4* LB) {
  const int tid = threadIdx.x;
  const int s0 = p.token_slot[2 * t], s1 = p.token_slot[2 * t + 1];
  const int e0 = p.top_idx[2 * t],   e1 = p.top_idx[2 * t + 1];
  const float w0 = p.top_w[2 * t],   w1 = p.top_w[2 * t + 1];
  float2 xv = ((const float2*)(p.x + (size_t)t * DMODEL))[tid];
  float s0x = 0, s0y = 0, s1x = 0, s1y = 0;
#pragma unroll
  for (int kh = 0; kh < 4; ++kh) {
    u32 a = *(const u32*)(p.part + (size_t)kh * PARTE + (size_t)s0 * DMODEL + 2 * tid);
    u32 b = *(const u32*)(p.part + (size_t)kh * PARTE + (size_t)s1 * DMODEL + 2 * tid);
    s0x += bf2f(a & 0xffffu); s0y += bf2f(a >> 16);
    s1x += bf2f(b & 0xffffu); s1y += bf2f(b >> 16);
  }
  float2 bb0 = ((const float2*)(p.b2 + (size_t)e0 * DMODEL))[tid];
  float2 bb1 = ((const float2*)(p.b2 + (size_t)e1 * DMODEL))[tid];
  float r0 = xv.x + w0 * (s0x + bb0.x) + w1 * (s1x + bb1.x);
  float r1 = xv.y + w0 * (s0y + bb0.y) + w1 * (s1y + bb1.y);
  float s = r0 + r1, sq = r0 * r0 + r1 * r1;
#pragma unroll
  for (int off = 32; off; off >>= 1) { s += __shfl_down(s, off); sq += __shfl_down(sq, off); }
  float* fr = (float*)LB;
  const int wv = tid >> 6;
  if ((tid & 63) == 0) { fr[wv] = s; fr[8 + wv] = sq; }
  __syncthreads();
  if (tid == 0) {
    float S = 0, Q = 0;
    for (int w = 0; w < 8; ++w) { S += fr[w]; Q += fr[8 + w]; }
    float mu = S * (1.0f / DMODEL);
    float var = Q * (1.0f / DMODEL) - mu * mu;
    fr[16] = mu; fr[17] = rsqrtf(var + 1e-5f);
  }
  __syncthreads();
  const float mu = fr[16], rsig = fr[17];
  float2 gv = ((const float2*)p.gamma)[tid];
  float2 bv = ((const float2*)p.beta)[tid];
  float2 o;
  o.x = (r0 - mu) * rsig * gv.x + bv.x;
  o.y = (r1 - mu) * rsig * gv.y + bv.y;
  ((float2*)(p.out + (size_t)t * DMODEL))[tid] = o;
  __syncthreads();
}

// ---- the persistent cooperative mega-kernel -----------------------------------
__global__ __launch_bounds__(512, 1) void k_moe(MoEP p) {
  __shared__ u32x4 LB[8192];        // 128KB
  __shared__ int wk;
  cg::grid_group gg = cg::this_grid();
  const int bid = blockIdx.x, tid = threadIdx.x;
  const int nb = gridDim.x;

  // P0: gating
  for (int t = bid; t < NTOK; t += nb) gating512(p, t, LB);
  __threadfence(); gg.sync();

  // P1a: offsets + tile map (single thread)
  if (bid == 0 && tid == 0) {
    int off = 0, nm = 0;
    for (int e = 0; e < NEXP; ++e) {
      p.poffset[e] = off;
      int nt = (p.counts[e] + BM - 1) / BM;
      for (int lt = 0; lt < nt; ++lt) p.mtile_e[nm++] = e;
      off += nt * BM;
    }
    for (; nm < MAX_MT; ++nm) p.mtile_e[nm] = -1;
  }
  __threadfence(); gg.sync();

  // P1b: scatter
  {
    int t = bid * 512 + tid;
    if (t < NTOK) {
      for (int k = 0; k < 2; ++k) {
        int e = p.top_idx[2 * t + k];
        int pos = atomicAdd(&p.cursor[e], 1);
        int slot = p.poffset[e] + pos;
        p.tok_of_slot[slot] = t;
        p.token_slot[2 * t + k] = slot;
      }
    }
  }
  __threadfence(); gg.sync();

  // P2: pool = preW1 (2048) + arrangeA (624)
  for (;;) {
    __syncthreads();
    if (tid == 0) wk = atomicAdd(&p.ctr[0], 1);
    __syncthreads();
    const int i = wk;
    if (i >= N_PREW1 + N_ARR) break;
    if (i < N_PREW1) prearr512(p.W1, p.Bp1, DMODEL, HFF, 16, 16, i, LB);
    else             arrangeA512(p, i - N_PREW1, LB);
  }
  __threadfence(); gg.sync();

  // P3: pool = GEMM1 (624) then preW2 (2048) backfilling the tail
  for (;;) {
    __syncthreads();
    if (tid == 0) wk = atomicAdd(&p.ctr[1], 1);
    __syncthreads();
    const int i = wk;
    if (i >= N_G1 + N_PREW2) break;
    if (i < N_G1) gemm1_item(p, i, LB);
    else          prearr512(p.W2, p.Bp2, HFF, DMODEL, 4, 64, i - N_G1, LB);
  }
  __threadfence(); gg.sync();

  // P4: GEMM2 split-K=4 (624 items)
  for (;;) {
    __syncthreads();
    if (tid == 0) wk = atomicAdd(&p.ctr[2], 1);
    __syncthreads();
    const int i = wk;
    if (i >= N_G2) break;
    gemm2_item(p, i, LB);
  }
  __threadfence(); gg.sync();

  // P5: combine + LayerNorm
  for (int t = bid; t < NTOK; t += nb) combine512(p, t, LB);
}

// ---------------- launch ----------------
extern "C" void kernel_launch(void* const* d_in, const int* in_sizes, int n_in,
                              void* d_out, int out_size, void* d_ws, size_t ws_size,
                              hipStream_t stream) {
  MoEP p;
  p.x     = (const float*)d_in[0];
  p.Wg    = (const float*)d_in[1];
  p.bg    = (const float*)d_in[2];
  p.W1    = (const float*)d_in[3];
  p.b1    = (const float*)d_in[4];
  p.W2    = (const float*)d_in[5];
  p.b2    = (const float*)d_in[6];
  p.gamma = (const float*)d_in[7];
  p.beta  = (const float*)d_in[8];
  p.out   = (float*)d_out;

  // ws (~226MB <= 237MB proven): [Ap1 19.5MiB | Bp1 64MiB | Bp2 64MiB | hImg 78MiB | meta]
  // part (78MiB, 4 bf16 partials) aliases [Ap1|Bp1] (dead after P3; grid.sync'd).
  char* ws = (char*)d_ws;
  const size_t szAp1 = (size_t)MAX_MT * KT1 * 2048 * 16;         // 19.5 MiB
  const size_t szBp  = (size_t)NEXP * DMODEL * HFF * 2;          // 64 MiB each
  p.Ap1  = (u32x4*)ws;
  p.Bp1  = (u32x4*)(ws + szAp1);
  p.part = (u16*)ws;                                             // alias
  p.Bp2  = (u32x4*)(ws + szAp1 + szBp);
  char* q = ws + szAp1 + 2 * szBp;
  p.hImg = (u32x4*)q; q += (size_t)MAX_MT * KT2 * 2048 * 16;     // 78 MiB
  int* meta = (int*)q;
  p.ctr         = meta;                      // 8
  p.counts      = meta + 8;                  // 8
  p.cursor      = meta + 16;                 // 8
  p.poffset     = meta + 24;                 // 8
  p.tok_of_slot = meta + 32;                 // 39*256 = 9984
  p.mtile_e     = p.tok_of_slot + MAX_MT * BM;   // 40
  p.token_slot  = p.mtile_e + 40;            // 8192
  p.top_idx     = p.token_slot + 2 * NTOK;   // 8192
  p.top_w       = (float*)(p.top_idx + 2 * NTOK);
  (void)ws_size; (void)in_sizes; (void)n_in; (void)out_size;

  // zero ctr/counts/cursor/poffset + tok_of_slot (pad rows -> token 0)
  hipMemsetAsync(meta, 0, (size_t)(32 + MAX_MT * BM) * 4, stream);

  void* kargs[] = { (void*)&p };
  hipLaunchCooperativeKernel((void*)k_moe, dim3(256), dim3(512), kargs, 0, stream);
}

// Round 13
// 492.848 us; speedup vs baseline: 2.1533x; 2.1533x over previous
//
#include <hip/hip_runtime.h>
#include <stdint.h>

#define NTOK   4096
#define DMODEL 1024
#define HFF    4096
#define NEXP   8
#define BM     256
#define BK     64
#define MAX_MT 39            // true bound: 8192/256 + 7 = 39
#define KT1    16            // DMODEL/BK
#define KT2    64            // HFF/BK
#define PARTE  ((size_t)MAX_MT * 256 * DMODEL)   // u16 elems per split-K partial

typedef unsigned int   u32;
typedef unsigned short u16;
typedef u32   u32x4  __attribute__((ext_vector_type(4)));
typedef short s16x8  __attribute__((ext_vector_type(8)));
typedef float f32x4  __attribute__((ext_vector_type(4)));

__device__ __forceinline__ u16 f2bf(float f) {
  u32 u = __builtin_bit_cast(u32, f);
  return (u16)((u + 0x7FFFu + ((u >> 16) & 1u)) >> 16);   // RNE, finite inputs
}
__device__ __forceinline__ float bf2f(u32 lo16) {
  return __builtin_bit_cast(float, lo16 << 16);
}

// async global->LDS, 16B/lane; LDS dest = wave-uniform base + lane*16
__device__ __forceinline__ void gld_lds16(const void* g, void* l) {
  __builtin_amdgcn_global_load_lds((const __attribute__((address_space(1))) void*)g,
                                   (__attribute__((address_space(3))) void*)l, 16, 0, 0);
}

// ---- fragment-image format (per 64k x 256n tile, 2048 u32x4 = 32KB) ----------
// entry g*64+l: g=(k>>5)*16+(n>>4), l=((k>>3)&3)*16+(n&15), elem j=k&7 -> T[k][n]
// Half k32 of tile t lives at image offset (2*t + k32)*1024 -- linear in halves.

// ------- W [K][N] fp32 -> fragment image tile (256 threads) --------------------
__device__ void prearr_dev(const float* __restrict__ W, u32x4* __restrict__ Bp,
                           int K, int N, int NT, int KT, int tile, u32x4* img4) {
  int kt  = tile % KT; int rem = tile / KT;
  int nt  = rem % NT;  int e   = rem / NT;
  u32* img = (u32*)img4;
  const int tid = threadIdx.x;
  const float* src = W + ((size_t)e * K + (size_t)kt * BK) * N + (size_t)nt * 256;
  const int c4 = (tid & 63) * 4;     // n: 0,4,...,252
  const int k0 = (tid >> 6) * 2;     // 0,2,4,6
#pragma unroll
  for (int p = 0; p < 8; ++p) {
    const int k = k0 + p * 8;        // even
    float4 v0 = *(const float4*)(src + (size_t)k * N + c4);
    float4 v1 = *(const float4*)(src + (size_t)(k + 1) * N + c4);
    u32 w[4] = { (u32)f2bf(v0.x) | ((u32)f2bf(v1.x) << 16),
                 (u32)f2bf(v0.y) | ((u32)f2bf(v1.y) << 16),
                 (u32)f2bf(v0.z) | ((u32)f2bf(v1.z) << 16),
                 (u32)f2bf(v0.w) | ((u32)f2bf(v1.w) << 16) };
#pragma unroll
    for (int q = 0; q < 4; ++q) {
      const int n = c4 + q;
      const int ent = ((k >> 5) * 16 + (n >> 4)) * 64 + ((k >> 3) & 3) * 16 + (n & 15);
      img[ent * 4 + ((k & 7) >> 1)] = w[q];
    }
  }
  __syncthreads();
  u32x4* outp = Bp + (size_t)tile * 2048;
#pragma unroll
  for (int c = 0; c < 8; ++c) outp[c * 256 + tid] = img4[c * 256 + tid];
}

// ---- gather tokens (fp32 x) -> A fragment image tile (256 threads) ------------
__device__ void arrange_dev(const float* __restrict__ x, const int* __restrict__ tok_of_slot,
                            const int* __restrict__ mtile_e, u32x4* __restrict__ Ap,
                            int j, u32x4* img) {
  const int mt = j >> 4, kt = j & 15;
  if (mtile_e[mt] < 0) return;
  u16* imgu = (u16*)img;
  const int tid = threadIdx.x;
  const int lane16 = tid & 15, rp = tid >> 4;
#pragma unroll
  for (int p = 0; p < 16; ++p) {
    const int row = rp + p * 16;
    const int tok = tok_of_slot[mt * BM + row];
    float4 v = *(const float4*)(x + (size_t)tok * DMODEL + kt * BK + lane16 * 4);
    const int g = (lane16 >> 3) * 16 + (row >> 4);
    const int l = ((lane16 >> 1) & 3) * 16 + (row & 15);
    u32* dst = (u32*)(imgu + (size_t)(g * 64 + l) * 8 + (lane16 & 1) * 4);
    dst[0] = (u32)f2bf(v.x) | ((u32)f2bf(v.y) << 16);
    dst[1] = (u32)f2bf(v.z) | ((u32)f2bf(v.w) << 16);
  }
  __syncthreads();
  u32x4* outp = Ap + (size_t)j * 2048;
#pragma unroll
  for (int c = 0; c < 8; ++c) outp[c * 256 + tid] = img[c * 256 + tid];
}

// ---- merged prep: preW1 (2048) | preW2 (2048) | arrange_a (624) ----------------
__global__ __launch_bounds__(256) void k_prep(
    const float* __restrict__ W1, const float* __restrict__ W2,
    u32x4* __restrict__ Bp1, u32x4* __restrict__ Bp2,
    const float* __restrict__ x, const int* __restrict__ tok_of_slot,
    const int* __restrict__ mtile_e, u32x4* __restrict__ Ap1) {
  __shared__ u32x4 img[2048];        // 32KB
  const int bid = blockIdx.x;
  if (bid < 2048)       prearr_dev(W1, Bp1, DMODEL, HFF, 16, 16, bid, img);
  else if (bid < 4096)  prearr_dev(W2, Bp2, HFF, DMODEL, 4, 64, bid - 2048, img);
  else                  arrange_dev(x, tok_of_slot, mtile_e, Ap1, bid - 4096, img);
}

// ---------------- gating: logits, top-2, softmax(2), counts ----------------
__global__ void k_gating(const float* __restrict__ x, const float* __restrict__ Wg,
                         const float* __restrict__ bg, int* __restrict__ top_idx,
                         float* __restrict__ top_w, int* __restrict__ counts) {
  int t = blockIdx.x, tid = threadIdx.x;
  float acc[NEXP];
#pragma unroll
  for (int e = 0; e < NEXP; ++e) acc[e] = 0.f;
  const float* xr = x + (size_t)t * DMODEL;
  for (int d = tid; d < DMODEL; d += 256) {
    float xv = xr[d];
    const float4* wg = (const float4*)(Wg + d * NEXP);
    float4 a = wg[0], b = wg[1];
    acc[0] += xv * a.x; acc[1] += xv * a.y; acc[2] += xv * a.z; acc[3] += xv * a.w;
    acc[4] += xv * b.x; acc[5] += xv * b.y; acc[6] += xv * b.z; acc[7] += xv * b.w;
  }
#pragma unroll
  for (int e = 0; e < NEXP; ++e)
#pragma unroll
    for (int off = 32; off; off >>= 1) acc[e] += __shfl_down(acc[e], off);
  __shared__ float red[4][NEXP];
  int w = tid >> 6;
  if ((tid & 63) == 0)
    for (int e = 0; e < NEXP; ++e) red[w][e] = acc[e];
  __syncthreads();
  if (tid == 0) {
    float v0 = -1e30f, v1 = -1e30f; int i0 = 0, i1 = 0;
    for (int e = 0; e < NEXP; ++e) {
      float l = red[0][e] + red[1][e] + red[2][e] + red[3][e] + bg[e];
      if (l > v0)      { v1 = v0; i1 = i0; v0 = l; i0 = e; }
      else if (l > v1) { v1 = l; i1 = e; }
    }
    float e1 = expf(v1 - v0);
    float w0 = 1.f / (1.f + e1);
    top_idx[2 * t] = i0; top_idx[2 * t + 1] = i1;
    top_w[2 * t] = w0;   top_w[2 * t + 1] = e1 * w0;
    atomicAdd(&counts[i0], 1); atomicAdd(&counts[i1], 1);
  }
}

// ------------ padded prefix offsets + compact live m-tile map ------------
__global__ void k_offsets(const int* __restrict__ counts, int* __restrict__ poffset,
                          int* __restrict__ mtile_e) {
  if (threadIdx.x == 0 && blockIdx.x == 0) {
    int off = 0, nm = 0;
    for (int e = 0; e < NEXP; ++e) {
      poffset[e] = off;
      int nt = (counts[e] + BM - 1) / BM;
      for (int lt = 0; lt < nt; ++lt) { mtile_e[nm] = e; ++nm; }
      off += nt * BM;
    }
    for (; nm < MAX_MT; ++nm) mtile_e[nm] = -1;
  }
}

// ---------------- scatter tokens to expert slots ----------------
__global__ void k_scatter(const int* __restrict__ top_idx, const int* __restrict__ poffset,
                          int* __restrict__ cursor, int* __restrict__ tok_of_slot,
                          int* __restrict__ token_slot) {
  int t = blockIdx.x * 256 + threadIdx.x;
  if (t >= NTOK) return;
  for (int k = 0; k < 2; ++k) {
    int e = top_idx[2 * t + k];
    int p = atomicAdd(&cursor[e], 1);
    int slot = poffset[e] + p;
    tok_of_slot[slot] = t;
    token_slot[2 * t + k] = slot;
  }
}

// ---------------- grouped GEMM, R8 ring schedule (best measured) ----------------
// 256x256xBK64 tile, 512 threads / 8 waves (2M x 4N), acc[8][4] per wave.
// 4-deep half-K-slab ring per operand (128KB LDS). Per half H: counted vmcnt
// (8/4/0 tail) -> raw s_barrier -> {stageA(H+3) | ds_read | 16 MFMA @prio1}
// -> {stageB(H+3) | ds_read | 16 MFMA @prio1}.
// MODE 1: full K (NH=32), GELU+bias, writes h as GEMM2 A-images.
// MODE 0: split-K=4 (kh from grid, NH=32 of 128), bf16 partial via swizzled-LDS
//         staging -> coalesced u32x4 row writes; bias deferred to combine.
template <int MODE>
__global__ __launch_bounds__(512, 2) void k_gemm(
    const u32x4* __restrict__ Ap, int halvesK,
    const u32x4* __restrict__ Bp,
    const float* __restrict__ bias, int Nfull, int NT,
    const int* __restrict__ mtile_e, void* __restrict__ outv) {
  const u32 nwg  = gridDim.x;
  const u32 orig = blockIdx.x;
  const u32 gsw  = (orig & 7u) * (nwg >> 3) + (orig >> 3);  // XCD chunks, mt-fastest
  const int mt = (int)(gsw % MAX_MT);
  const u32 q  = gsw / MAX_MT;
  int nt, kh, Hbase, NH;
  if (MODE) { nt = (int)q; kh = 0; Hbase = 0; NH = halvesK; }
  else      { nt = (int)(q & 3); kh = (int)(q >> 2);
              NH = halvesK / 4; Hbase = kh * NH; }
  const int e = mtile_e[mt];
  if (e < 0) return;

  __shared__ u32x4 LB[8192];          // 128KB; A ring [0,4096), B ring [4096,8192)
  u32x4* AsR = LB;
  u32x4* BsR = LB + 4096;

  const int tid  = threadIdx.x;
  const int lane = tid & 63;
  const int wv   = tid >> 6;          // 0..7
  const int wm   = wv >> 2;           // 0..1
  const int wn   = wv & 3;            // 0..3

  const u32x4* abase = Ap + ((size_t)mt * halvesK + Hbase) * 1024;
  const u32x4* bbase = Bp + ((size_t)(e * NT + nt) * halvesK + Hbase) * 1024;

  auto stageA = [&](int Hs) {
    const u32x4* sa = abase + (size_t)Hs * 1024;
    const int s = Hs & 3;
    gld_lds16(sa + (wv * 2 + 0) * 64 + lane, &AsR[s * 1024 + (wv * 2 + 0) * 64]);
    gld_lds16(sa + (wv * 2 + 1) * 64 + lane, &AsR[s * 1024 + (wv * 2 + 1) * 64]);
  };
  auto stageB = [&](int Hs) {
    const u32x4* sb = bbase + (size_t)Hs * 1024;
    const int s = Hs & 3;
    gld_lds16(sb + (wv * 2 + 0) * 64 + lane, &BsR[s * 1024 + (wv * 2 + 0) * 64]);
    gld_lds16(sb + (wv * 2 + 1) * 64 + lane, &BsR[s * 1024 + (wv * 2 + 1) * 64]);
  };

  f32x4 acc[8][4] = {};

  stageA(0); stageB(0); stageA(1); stageB(1); stageA(2); stageB(2);  // 12 in flight

  for (int H = 0; H < NH; ++H) {
    const int rem = NH - 1 - H;
    if (rem >= 2)      asm volatile("s_waitcnt vmcnt(8)" ::: "memory");
    else if (rem == 1) asm volatile("s_waitcnt vmcnt(4)" ::: "memory");
    else               asm volatile("s_waitcnt vmcnt(0)" ::: "memory");
    __builtin_amdgcn_sched_barrier(0);
    __builtin_amdgcn_s_barrier();     // slab H complete in all waves; H-1 readers done
    __builtin_amdgcn_sched_barrier(0);
    const u32x4* Ah = AsR + (H & 3) * 1024;
    const u32x4* Bh = BsR + (H & 3) * 1024;
    const bool st = (H + 3 < NH);
    // ---- phase 0: stage A of H+3, read b[0..3]+a[0..3], 16 MFMA
    if (st) stageA(H + 3);
    __builtin_amdgcn_sched_barrier(0);
    s16x8 a[4], b[4];
#pragma unroll
    for (int ni = 0; ni < 4; ++ni)
      b[ni] = __builtin_bit_cast(s16x8, Bh[(wn * 4 + ni) * 64 + lane]);
#pragma unroll
    for (int mi = 0; mi < 4; ++mi)
      a[mi] = __builtin_bit_cast(s16x8, Ah[(wm * 8 + mi) * 64 + lane]);
    __builtin_amdgcn_s_setprio(1);
#pragma unroll
    for (int mi = 0; mi < 4; ++mi)
#pragma unroll
      for (int ni = 0; ni < 4; ++ni)
        acc[mi][ni] = __builtin_amdgcn_mfma_f32_16x16x32_bf16(a[mi], b[ni], acc[mi][ni], 0, 0, 0);
    __builtin_amdgcn_s_setprio(0);
    __builtin_amdgcn_sched_barrier(0);
    // ---- phase 1: stage B of H+3, read a[4..7], 16 MFMA
    if (st) stageB(H + 3);
    __builtin_amdgcn_sched_barrier(0);
#pragma unroll
    for (int mi = 0; mi < 4; ++mi)
      a[mi] = __builtin_bit_cast(s16x8, Ah[(wm * 8 + 4 + mi) * 64 + lane]);
    __builtin_amdgcn_s_setprio(1);
#pragma unroll
    for (int mi = 0; mi < 4; ++mi)
#pragma unroll
      for (int ni = 0; ni < 4; ++ni)
        acc[4 + mi][ni] = __builtin_amdgcn_mfma_f32_16x16x32_bf16(a[mi], b[ni], acc[4 + mi][ni], 0, 0, 0);
    __builtin_amdgcn_s_setprio(0);
  }

  __syncthreads();                    // all reads done; LDS free for epilogue

  const int rbase = ((lane >> 4) << 2);
  const int c16 = lane & 15;
  if (MODE) {
    // ---- GELU+bias; scatter to image layout in LDS; write 4 GEMM2 A-tiles
    u16* cimg = (u16*)LB;
    float bv[4];
#pragma unroll
    for (int ni = 0; ni < 4; ++ni)
      bv[ni] = bias[(size_t)e * Nfull + nt * 256 + wn * 64 + ni * 16 + c16];
#pragma unroll
    for (int mi = 0; mi < 8; ++mi)
#pragma unroll
      for (int ni = 0; ni < 4; ++ni)
#pragma unroll
        for (int r = 0; r < 4; ++r) {
          const int row = wm * 128 + mi * 16 + rbase + r;
          const int col = wn * 64 + ni * 16 + c16;
          float v = acc[mi][ni][r] + bv[ni];
          v = 0.5f * v * (1.0f + erff(v * 0.70710678118654752f));
          const int k = col & 63;
          const int ent = (col >> 6) * 2048
                        + ((k >> 5) * 16 + (row >> 4)) * 64
                        + ((k >> 3) & 3) * 16 + (row & 15);
          cimg[ent * 8 + (k & 7)] = f2bf(v);
        }
    __syncthreads();
    u32x4* outp = (u32x4*)outv + ((size_t)mt * KT2 + nt * 4) * 2048;
#pragma unroll
    for (int c = 0; c < 16; ++c) {
      const int idx = c * 512 + tid;
      outp[idx] = LB[idx];
    }
  } else {
    // ---- bf16 split-K partial via swizzled LDS (cimg u16[256][256]) -> coalesced
    u16* cimg = (u16*)LB;
#pragma unroll
    for (int mi = 0; mi < 8; ++mi)
#pragma unroll
      for (int ni = 0; ni < 4; ++ni)
#pragma unroll
        for (int r = 0; r < 4; ++r) {
          const int row = wm * 128 + mi * 16 + rbase + r;
          const int col = wn * 64 + ni * 16 + c16;
          const int ch = col >> 3;
          cimg[row * 256 + ((ch ^ (row & 31)) << 3) + (col & 7)] = f2bf(acc[mi][ni][r]);
        }
    __syncthreads();
    u16* o = (u16*)outv + (size_t)kh * PARTE + (size_t)mt * 256 * DMODEL + nt * 256;
#pragma unroll
    for (int c = 0; c < 16; ++c) {
      const int cid = c * 512 + tid;
      const int row = cid >> 5, ch = cid & 31;
      *(u32x4*)&o[(size_t)row * DMODEL + ch * 8] = LB[row * 32 + (ch ^ (row & 31))];
    }
  }
}

// -------- combine: sum 4 bf16 partials + bias, top-2 weight, residual, LN ------
__global__ void k_combine_ln(const float* __restrict__ x, const u16* __restrict__ part,
                             const int* __restrict__ token_slot, const int* __restrict__ top_idx,
                             const float* __restrict__ top_w, const float* __restrict__ b2,
                             const float* __restrict__ gamma, const float* __restrict__ beta,
                             float* __restrict__ out) {
  int t = blockIdx.x, tid = threadIdx.x;
  int s0 = token_slot[2 * t], s1 = token_slot[2 * t + 1];
  int e0 = top_idx[2 * t],   e1 = top_idx[2 * t + 1];
  float w0 = top_w[2 * t], w1 = top_w[2 * t + 1];
  float4 xv = ((const float4*)(x + (size_t)t * DMODEL))[tid];
  float y0[4] = {}, y1[4] = {};
  const size_t i0 = (size_t)s0 * DMODEL + tid * 4;
  const size_t i1 = (size_t)s1 * DMODEL + tid * 4;
#pragma unroll
  for (int kh = 0; kh < 4; ++kh) {
    uint2 a = *(const uint2*)(part + kh * PARTE + i0);
    uint2 b = *(const uint2*)(part + kh * PARTE + i1);
    y0[0] += bf2f(a.x & 0xffffu); y0[1] += bf2f(a.x >> 16);
    y0[2] += bf2f(a.y & 0xffffu); y0[3] += bf2f(a.y >> 16);
    y1[0] += bf2f(b.x & 0xffffu); y1[1] += bf2f(b.x >> 16);
    y1[2] += bf2f(b.y & 0xffffu); y1[3] += bf2f(b.y >> 16);
  }
  float4 bb0 = ((const float4*)(b2 + (size_t)e0 * DMODEL))[tid];
  float4 bb1 = ((const float4*)(b2 + (size_t)e1 * DMODEL))[tid];
  float r0 = xv.x + w0 * (y0[0] + bb0.x) + w1 * (y1[0] + bb1.x);
  float r1 = xv.y + w0 * (y0[1] + bb0.y) + w1 * (y1[1] + bb1.y);
  float r2 = xv.z + w0 * (y0[2] + bb0.z) + w1 * (y1[2] + bb1.z);
  float r3 = xv.w + w0 * (y0[3] + bb0.w) + w1 * (y1[3] + bb1.w);
  float s  = r0 + r1 + r2 + r3;
  float sq = r0 * r0 + r1 * r1 + r2 * r2 + r3 * r3;
#pragma unroll
  for (int off = 32; off; off >>= 1) { s += __shfl_down(s, off); sq += __shfl_down(sq, off); }
  __shared__ float rs[4], rq[4];
  __shared__ float mu_s, rsig_s;
  int w = tid >> 6;
  if ((tid & 63) == 0) { rs[w] = s; rq[w] = sq; }
  __syncthreads();
  if (tid == 0) {
    float S = rs[0] + rs[1] + rs[2] + rs[3];
    float Q = rq[0] + rq[1] + rq[2] + rq[3];
    float mu  = S * (1.0f / DMODEL);
    float var = Q * (1.0f / DMODEL) - mu * mu;
    mu_s = mu; rsig_s = rsqrtf(var + 1e-5f);
  }
  __syncthreads();
  float mu = mu_s, rsig = rsig_s;
  float4 gv = ((const float4*)gamma)[tid];
  float4 bv = ((const float4*)beta)[tid];
  float4 o;
  o.x = (r0 - mu) * rsig * gv.x + bv.x;
  o.y = (r1 - mu) * rsig * gv.y + bv.y;
  o.z = (r2 - mu) * rsig * gv.z + bv.z;
  o.w = (r3 - mu) * rsig * gv.w + bv.w;
  ((float4*)(out + (size_t)t * DMODEL))[tid] = o;
}

// ---------------- launch ----------------
extern "C" void kernel_launch(void* const* d_in, const int* in_sizes, int n_in,
                              void* d_out, int out_size, void* d_ws, size_t ws_size,
                              hipStream_t stream) {
  const float* x     = (const float*)d_in[0];
  const float* Wg    = (const float*)d_in[1];
  const float* bg    = (const float*)d_in[2];
  const float* W1    = (const float*)d_in[3];
  const float* b1    = (const float*)d_in[4];
  const float* W2    = (const float*)d_in[5];
  const float* b2    = (const float*)d_in[6];
  const float* gamma = (const float*)d_in[7];
  const float* beta  = (const float*)d_in[8];
  float* out = (float*)d_out;

  // ws ~236.6MB: [Ap1 19.5MiB | Bp1 64MiB][Bp2 64MiB][hImg 78MiB][meta]
  // part (78MiB, 4 bf16 partials) aliases [Ap1|Bp1] (dead after GEMM1).
  char* ws = (char*)d_ws;
  const size_t szAp1 = (size_t)MAX_MT * KT1 * 2048 * 16;         // 19.5 MiB
  const size_t szBp  = (size_t)NEXP * DMODEL * HFF * 2;          // 64 MiB
  u32x4* Ap1  = (u32x4*)ws;
  u32x4* Bp1  = (u32x4*)(ws + szAp1);
  u16*   part = (u16*)ws;                                        // alias
  u32x4* Bp2  = (u32x4*)(ws + szAp1 + szBp);
  char* p = ws + szAp1 + 2 * szBp;
  u16*   hImg = (u16*)p;  p += (size_t)MAX_MT * KT2 * 2048 * 16; // 78 MiB
  int*   meta = (int*)p;
  int*   counts      = meta;
  int*   cursor      = counts + 8;
  int*   poffset     = cursor + 8;
  int*   tok_of_slot = poffset + 8;
  int*   mtile_e     = tok_of_slot + MAX_MT * BM;
  int*   token_slot  = mtile_e + MAX_MT;
  int*   top_idx     = token_slot + 2 * NTOK;
  float* top_w       = (float*)(top_idx + 2 * NTOK);
  (void)ws_size; (void)in_sizes; (void)n_in; (void)out_size;

  hipMemsetAsync(meta, 0, (size_t)(24 + MAX_MT * BM) * 4, stream);

  k_gating<<<NTOK, 256, 0, stream>>>(x, Wg, bg, top_idx, top_w, counts);
  k_offsets<<<1, 1, 0, stream>>>(counts, poffset, mtile_e);
  k_scatter<<<NTOK / 256, 256, 0, stream>>>(top_idx, poffset, cursor, tok_of_slot, token_slot);

  // merged prep: preW1 (2048) + preW2 (2048) + arrange_a (624) = 4720 blocks
  k_prep<<<2048 + 2048 + MAX_MT * KT1, 256, 0, stream>>>(
      W1, W2, Bp1, Bp2, x, tok_of_slot, mtile_e, Ap1);

  // GEMM1: 16 nt x 39 mt = 624 blocks (8*78); GELU; writes h as GEMM2 A-images
  k_gemm<1><<<(HFF / 256) * MAX_MT, 512, 0, stream>>>(
      Ap1, 2 * KT1, Bp1, b1, HFF, HFF / 256, mtile_e, (void*)hImg);

  // GEMM2: 4 nt x 39 mt x 4 kh = 624 blocks (8*78); bf16 partials -> part
  k_gemm<0><<<(DMODEL / 256) * MAX_MT * 4, 512, 0, stream>>>(
      (const u32x4*)hImg, 2 * KT2, Bp2, nullptr, DMODEL, DMODEL / 256,
      mtile_e, (void*)part);

  k_combine_ln<<<NTOK, 256, 0, stream>>>(x, part, token_slot, top_idx, top_w,
                                         b2, gamma, beta, out);
}